// Round 3
// baseline (3598.422 us; speedup 1.0000x reference)
//
#include <hip/hip_runtime.h>

#define BB 8
#define IMG 224
#define DD 768
#define NLAY 12
#define DI 1536
#define DS 16
#define DTR 48
#define NPATCH 196
#define L_SEQ 196
#define M_ROWS 1568   // BB*NPATCH
#define DCONV 4

typedef _Float16 f16x8 __attribute__((ext_vector_type(8)));
typedef _Float16 f16x4 __attribute__((ext_vector_type(4)));
typedef float f32x4 __attribute__((ext_vector_type(4)));

// ---------------- split fp32 -> (hi,lo) f16 planes, 4 elems/thread ----------------
__global__ __launch_bounds__(256) void split4_k(const float* __restrict__ in,
    _Float16* __restrict__ hi, _Float16* __restrict__ lo, int n4)
{
    int i = blockIdx.x * 256 + threadIdx.x;
    if (i >= n4) return;
    float4 v = ((const float4*)in)[i];
    _Float16 h0 = (_Float16)v.x, h1 = (_Float16)v.y, h2 = (_Float16)v.z, h3 = (_Float16)v.w;
    f16x4 H = {h0, h1, h2, h3};
    f16x4 L = {(_Float16)(v.x - (float)h0), (_Float16)(v.y - (float)h1),
               (_Float16)(v.z - (float)h2), (_Float16)(v.w - (float)h3)};
    ((f16x4*)hi)[i] = H;
    ((f16x4*)lo)[i] = L;
}

// ---------------- im2col with split output: x (B,3,224,224) -> Xp hi/lo (1568 x 768) ----------------
__global__ __launch_bounds__(256) void im2col_k(const float* __restrict__ x,
    _Float16* __restrict__ hi, _Float16* __restrict__ lo)
{
    int idx = blockIdx.x * 256 + threadIdx.x;
    if (idx >= M_ROWS * DD) return;
    int k = idx % DD;
    int m = idx / DD;
    int b = m / NPATCH;
    int t = m % NPATCH;
    int i = t / 14, j = t % 14;
    int c = k / 256;
    int pq = k % 256;
    int p = pq / 16, q = pq % 16;
    float v = x[(((size_t)b * 3 + c) * IMG + i * 16 + p) * IMG + j * 16 + q];
    _Float16 h = (_Float16)v;
    hi[idx] = h;
    lo[idx] = (_Float16)(v - (float)h);
}

// ---------------- f16x3 MFMA GEMM: C[M,N] = (Ah+Al)[M,K] * (Bh+Bl)[N,K]^T (fp32-ish accuracy) ----
// BM=128 BN=64 BK=32, 256 thr = 4 waves (2x2), each wave 64x32 = 4x2 frags of 16x16.
// mode 0: plain store   mode 2: += bias[n] + pos[(m%196)*N+n]
// Chi/Clo non-null: also store f16 hi/lo split of C.
__global__ __launch_bounds__(256) void mgemm_k(
    const _Float16* __restrict__ Ah, const _Float16* __restrict__ Al,
    const _Float16* __restrict__ Bh, const _Float16* __restrict__ Bl,
    float* __restrict__ C, _Float16* __restrict__ Chi, _Float16* __restrict__ Clo,
    int M, int N, int K,
    const float* __restrict__ bias, const float* __restrict__ pos, int mode)
{
    __shared__ _Float16 As[2][128][40];   // [plane][m][k], 40-half row stride
    __shared__ _Float16 Bs[2][64][40];
    int tid = threadIdx.x;
    int m0 = blockIdx.y * 128, n0 = blockIdx.x * 64;
    int lane = tid & 63;
    int wid = tid >> 6;
    int wM = (wid >> 1) * 64, wN = (wid & 1) * 32;
    int lm = lane & 15, quad = lane >> 4;

    f32x4 acc[4][2] = {};

    int apl = tid >> 7, arow = tid & 127;
    int bpl = tid >> 7, brow = (tid >> 1) & 63, bseg = tid & 1;
    const _Float16* Asrc = apl ? Al : Ah;
    const _Float16* Bsrc = bpl ? Bl : Bh;
    int gm = m0 + arow;
    int gn = n0 + brow;

    for (int k0 = 0; k0 < K; k0 += 32) {
        float4 av0 = make_float4(0.f,0.f,0.f,0.f), av1 = av0, av2 = av0, av3 = av0;
        if (gm < M) {
            const float4* p = (const float4*)&Asrc[(size_t)gm * K + k0];
            av0 = p[0]; av1 = p[1]; av2 = p[2]; av3 = p[3];
        }
        const float4* q = (const float4*)&Bsrc[(size_t)gn * K + k0 + bseg * 16];
        float4 bv0 = q[0], bv1 = q[1];
        *(float4*)&As[apl][arow][0]  = av0;
        *(float4*)&As[apl][arow][8]  = av1;
        *(float4*)&As[apl][arow][16] = av2;
        *(float4*)&As[apl][arow][24] = av3;
        *(float4*)&Bs[bpl][brow][bseg * 16]     = bv0;
        *(float4*)&Bs[bpl][brow][bseg * 16 + 8] = bv1;
        __syncthreads();

        f16x8 a_h[4], a_l[4], b_h[2], b_l[2];
#pragma unroll
        for (int mi = 0; mi < 4; ++mi) {
            a_h[mi] = *(const f16x8*)&As[0][wM + mi * 16 + lm][quad * 8];
            a_l[mi] = *(const f16x8*)&As[1][wM + mi * 16 + lm][quad * 8];
        }
#pragma unroll
        for (int ni = 0; ni < 2; ++ni) {
            b_h[ni] = *(const f16x8*)&Bs[0][wN + ni * 16 + lm][quad * 8];
            b_l[ni] = *(const f16x8*)&Bs[1][wN + ni * 16 + lm][quad * 8];
        }
#pragma unroll
        for (int mi = 0; mi < 4; ++mi)
#pragma unroll
            for (int ni = 0; ni < 2; ++ni) {
                acc[mi][ni] = __builtin_amdgcn_mfma_f32_16x16x32_f16(a_h[mi], b_h[ni], acc[mi][ni], 0, 0, 0);
                acc[mi][ni] = __builtin_amdgcn_mfma_f32_16x16x32_f16(a_h[mi], b_l[ni], acc[mi][ni], 0, 0, 0);
                acc[mi][ni] = __builtin_amdgcn_mfma_f32_16x16x32_f16(a_l[mi], b_h[ni], acc[mi][ni], 0, 0, 0);
            }
        __syncthreads();
    }

#pragma unroll
    for (int mi = 0; mi < 4; ++mi)
#pragma unroll
        for (int ni = 0; ni < 2; ++ni)
#pragma unroll
            for (int r = 0; r < 4; ++r) {
                int row = m0 + wM + mi * 16 + quad * 4 + r;
                if (row >= M) continue;
                int col = n0 + wN + ni * 16 + lm;
                float v = acc[mi][ni][r];
                if (mode == 2) v += bias[col] + pos[(size_t)(row % NPATCH) * N + col];
                size_t idx = (size_t)row * N + col;
                C[idx] = v;
                if (Chi) {
                    _Float16 h = (_Float16)v;
                    Chi[idx] = h;
                    Clo[idx] = (_Float16)(v - (float)h);
                }
            }
}

// ---------------- generic tiled fp32 GEMM (kept for x_proj / dt_proj) ----------------
// mode 1: softplus(acc + bias[n])    mode 3: atomicAdd (split-K over gridDim.z)
__global__ __launch_bounds__(256) void gemm_k(
    const float* __restrict__ A, int lda,
    const float* __restrict__ Bw,
    float* __restrict__ C,
    int M, int N, int K,
    const float* __restrict__ bias,
    int mode)
{
    __shared__ __align__(16) float As[16][68];
    __shared__ __align__(16) float Bs[16][68];
    int tid = threadIdx.x;
    int m0 = blockIdx.y * 64;
    int n0 = blockIdx.x * 64;
    int tx = tid & 15;
    int ty = tid >> 4;
    float acc[4][4] = {};
    int lrow = tid >> 2;
    int lk4  = (tid & 3) << 2;
    int kPer = K / gridDim.z;
    int kBeg = blockIdx.z * kPer;
    for (int k0 = kBeg; k0 < kBeg + kPer; k0 += 16) {
        {
            int m = m0 + lrow;
            float4 va = make_float4(0.f, 0.f, 0.f, 0.f);
            if (m < M) va = *(const float4*)&A[(size_t)m * lda + k0 + lk4];
            As[lk4 + 0][lrow] = va.x; As[lk4 + 1][lrow] = va.y;
            As[lk4 + 2][lrow] = va.z; As[lk4 + 3][lrow] = va.w;
        }
        {
            int n = n0 + lrow;
            float4 vb = make_float4(0.f, 0.f, 0.f, 0.f);
            if (n < N) vb = *(const float4*)&Bw[(size_t)n * K + k0 + lk4];
            Bs[lk4 + 0][lrow] = vb.x; Bs[lk4 + 1][lrow] = vb.y;
            Bs[lk4 + 2][lrow] = vb.z; Bs[lk4 + 3][lrow] = vb.w;
        }
        __syncthreads();
#pragma unroll
        for (int kk = 0; kk < 16; ++kk) {
            float4 a4 = *(const float4*)&As[kk][ty * 4];
            float4 b4 = *(const float4*)&Bs[kk][tx * 4];
            float av[4] = {a4.x, a4.y, a4.z, a4.w};
            float bv[4] = {b4.x, b4.y, b4.z, b4.w};
#pragma unroll
            for (int i = 0; i < 4; ++i)
#pragma unroll
                for (int j = 0; j < 4; ++j)
                    acc[i][j] += av[i] * bv[j];
        }
        __syncthreads();
    }
#pragma unroll
    for (int i = 0; i < 4; ++i) {
        int m = m0 + ty * 4 + i;
        if (m >= M) continue;
#pragma unroll
        for (int j = 0; j < 4; ++j) {
            int n = n0 + tx * 4 + j;
            if (n >= N) continue;
            float v = acc[i][j];
            if (mode == 1) {
                v += bias[n];
                v = (v > 20.f) ? v : log1pf(__expf(v));
            }
            if (mode == 3) atomicAdd(&C[(size_t)m * N + n], v);
            else           C[(size_t)m * N + n] = v;
        }
    }
}

// ---------------- causal depthwise conv (k=4) + SiLU ----------------
__global__ __launch_bounds__(256) void conv_k(
    const float* __restrict__ xz, const float* __restrict__ cw,
    const float* __restrict__ cb, float* __restrict__ xc)
{
    int idx = blockIdx.x * 256 + threadIdx.x;
    if (idx >= M_ROWS * DI) return;
    int e = idx % DI;
    int m = idx / DI;
    int l = m % L_SEQ;
    float acc = cb[e];
#pragma unroll
    for (int k = 0; k < DCONV; ++k) {
        int ls = l + k - (DCONV - 1);
        if (ls >= 0) acc += cw[e * DCONV + k] * xz[(size_t)(m + k - (DCONV - 1)) * (2 * DI) + e];
    }
    xc[idx] = acc / (1.f + __expf(-acc));
}

// ---------------- selective scan, state-parallel ----------------
// lane = (channel c in [0,4)) * 16 + (state s in [0,16)); wave = 4 channels;
// block = 256 thr = 16 channels; grid = (DI/16, B) = (96, 8) = 768 blocks.
__global__ __launch_bounds__(256) void scan_k(
    const float* __restrict__ dt, const float* __restrict__ xc,
    const float* __restrict__ proj, const float* __restrict__ xz,
    const float* __restrict__ A_log, const float* __restrict__ Dp,
    _Float16* __restrict__ yh, _Float16* __restrict__ yl)
{
    int tid = threadIdx.x;
    int wid = tid >> 6, lane = tid & 63;
    int c = lane >> 4, s = lane & 15;
    int d = blockIdx.x * 16 + wid * 4 + c;
    int b = blockIdx.y;

    float Aa = -__expf(A_log[d * DS + s]);
    float dP = Dp[d];
    float h = 0.f;
    size_t base0 = (size_t)b * L_SEQ;

    // software pipeline: prefetch step 0
    float dtv = dt[base0 * DI + d];
    float xv  = xc[base0 * DI + d];
    float zv  = xz[base0 * 2 * DI + DI + d];
    float Bv  = proj[base0 * 80 + DTR + s];
    float Cv  = proj[base0 * 80 + DTR + DS + s];

    for (int l = 0; l < L_SEQ; ++l) {
        float ndt = 0.f, nx = 0.f, nz = 0.f, nB = 0.f, nC = 0.f;
        if (l + 1 < L_SEQ) {
            size_t nb = base0 + l + 1;
            ndt = dt[nb * DI + d];
            nx  = xc[nb * DI + d];
            nz  = xz[nb * 2 * DI + DI + d];
            nB  = proj[nb * 80 + DTR + s];
            nC  = proj[nb * 80 + DTR + DS + s];
        }
        float a = __expf(dtv * Aa);
        h = a * h + (dtv * xv) * Bv;
        float p = h * Cv;
        p += __shfl_xor(p, 1, 16);
        p += __shfl_xor(p, 2, 16);
        p += __shfl_xor(p, 4, 16);
        p += __shfl_xor(p, 8, 16);
        if (s == 0) {
            float yv = p + xv * dP;
            float sg = 1.f / (1.f + __expf(-zv));
            float vy = yv * (zv * sg);
            size_t oidx = (base0 + l) * DI + d;
            _Float16 hh = (_Float16)vy;
            yh[oidx] = hh;
            yl[oidx] = (_Float16)(vy - (float)hh);
        }
        dtv = ndt; xv = nx; zv = nz; Bv = nB; Cv = nC;
    }
}

// ---------------- layernorm over D=768 ----------------
__global__ __launch_bounds__(256) void ln_k(const float* __restrict__ h,
    const float* __restrict__ w, const float* __restrict__ bias, float* __restrict__ out)
{
    int row = blockIdx.x;
    int tid = threadIdx.x;
    const float* hr = h + (size_t)row * DD;
    float v0 = hr[tid], v1 = hr[tid + 256], v2 = hr[tid + 512];
    float s = v0 + v1 + v2;
    __shared__ float red[4];
    for (int off = 32; off; off >>= 1) s += __shfl_down(s, off);
    if ((tid & 63) == 0) red[tid >> 6] = s;
    __syncthreads();
    float mu = (red[0] + red[1] + red[2] + red[3]) * (1.f / 768.f);
    __syncthreads();
    float d0 = v0 - mu, d1 = v1 - mu, d2 = v2 - mu;
    float vs = d0 * d0 + d1 * d1 + d2 * d2;
    for (int off = 32; off; off >>= 1) vs += __shfl_down(vs, off);
    if ((tid & 63) == 0) red[tid >> 6] = vs;
    __syncthreads();
    float var = (red[0] + red[1] + red[2] + red[3]) * (1.f / 768.f);
    float rs = rsqrtf(var + 1e-5f);
    out[(size_t)row * DD + tid]       = d0 * rs * w[tid]       + bias[tid];
    out[(size_t)row * DD + tid + 256] = d1 * rs * w[tid + 256] + bias[tid + 256];
    out[(size_t)row * DD + tid + 512] = d2 * rs * w[tid + 512] + bias[tid + 512];
}

__global__ __launch_bounds__(256) void fill0_k(float* __restrict__ p, int n) {
    int i = blockIdx.x * 256 + threadIdx.x;
    if (i < n) p[i] = 0.f;
}

extern "C" void kernel_launch(void* const* d_in, const int* in_sizes, int n_in,
                              void* d_out, int out_size, void* d_ws, size_t ws_size,
                              hipStream_t stream) {
    const float* x        = (const float*)d_in[0];
    const float* patch_w  = (const float*)d_in[1];
    const float* patch_b  = (const float*)d_in[2];
    const float* pos      = (const float*)d_in[3];
    const float* in_proj  = (const float*)d_in[4];
    const float* conv_w   = (const float*)d_in[5];
    const float* conv_b   = (const float*)d_in[6];
    const float* x_proj   = (const float*)d_in[7];
    const float* dt_w     = (const float*)d_in[8];
    const float* dt_b     = (const float*)d_in[9];
    const float* A_log    = (const float*)d_in[10];
    const float* D_param  = (const float*)d_in[11];
    const float* out_w    = (const float*)d_in[12];
    const float* norm_w   = (const float*)d_in[13];
    const float* norm_b   = (const float*)d_in[14];
    float* out = (float*)d_out;

    // fp32 workspace
    float* ws    = (float*)d_ws;
    float* hbuf  = ws;                      // 1,204,224
    float* xzb   = hbuf  + 1204224;         // 4,816,896
    float* xcb   = xzb   + 4816896;         // 2,408,448
    float* projb = xcb   + 2408448;         //   125,440
    float* dtb   = projb + 125440;          // 2,408,448
    // f16 split workspace
    _Float16* h16 = (_Float16*)(dtb + 2408448);
    _Float16* hbh = h16;                    // 1,204,224
    _Float16* hbl = hbh + 1204224;          // 1,204,224
    _Float16* yh  = hbl + 1204224;          // 2,408,448 (also holds im2col hi at start)
    _Float16* yl  = yh  + 2408448;          // 2,408,448
    _Float16* pwh = yl  + 2408448;          //   589,824
    _Float16* pwl = pwh + 589824;
    _Float16* wih = pwl + 589824;           // 2,359,296 (per-layer in_proj_w split, reused)
    _Float16* wil = wih + 2359296;
    _Float16* woh = wil + 2359296;          // 1,179,648 (per-layer out_proj_w split, reused)
    _Float16* wol = woh + 1179648;

    // patch embed: split patch_w, im2col-split, MFMA GEMM (+bias+pos, emit hbuf splits)
    split4_k<<<(589824 / 4 + 255) / 256, 256, 0, stream>>>(patch_w, pwh, pwl, 589824 / 4);
    im2col_k<<<(M_ROWS * DD + 255) / 256, 256, 0, stream>>>(x, yh, yl);
    mgemm_k<<<dim3(DD / 64, (M_ROWS + 127) / 128), 256, 0, stream>>>(
        yh, yl, pwh, pwl, hbuf, hbh, hbl, M_ROWS, DD, DD, patch_b, pos, 2);

    for (int l = 0; l < NLAY; ++l) {
        // split this layer's big weights
        split4_k<<<(2359296 / 4 + 255) / 256, 256, 0, stream>>>(
            in_proj + (size_t)l * 2 * DI * DD, wih, wil, 2359296 / 4);
        split4_k<<<(1179648 / 4 + 255) / 256, 256, 0, stream>>>(
            out_w + (size_t)l * DD * DI, woh, wol, 1179648 / 4);
        // in_proj: (1568,768) x (3072,768)^T -> xz (fp32)
        mgemm_k<<<dim3(2 * DI / 64, (M_ROWS + 127) / 128), 256, 0, stream>>>(
            hbh, hbl, wih, wil, xzb, nullptr, nullptr, M_ROWS, 2 * DI, DD, nullptr, nullptr, 0);
        // causal conv + silu -> xc
        conv_k<<<(M_ROWS * DI) / 256, 256, 0, stream>>>(xzb, conv_w + (size_t)l * DI * DCONV,
                                                        conv_b + (size_t)l * DI, xcb);
        // x_proj (N=80 skinny): split-K=4 atomicAdd
        fill0_k<<<(M_ROWS * 80 + 255) / 256, 256, 0, stream>>>(projb, M_ROWS * 80);
        gemm_k<<<dim3(2, 25, 4), 256, 0, stream>>>(xcb, DI, x_proj + (size_t)l * 80 * DI, projb,
                                                   M_ROWS, 80, DI, nullptr, 3);
        // dt_proj: proj[:, :48] x (1536,48)^T + bias -> softplus
        gemm_k<<<dim3(24, 25), 256, 0, stream>>>(projb, 80, dt_w + (size_t)l * DI * DTR, dtb,
                                                 M_ROWS, DI, DTR, dt_b + (size_t)l * DI, 1);
        // selective scan + D skip + silu(z) gate -> y split (state-parallel)
        scan_k<<<dim3(DI / 16, BB), 256, 0, stream>>>(dtb, xcb, projb, xzb,
                                                      A_log + (size_t)l * DI * DS,
                                                      D_param + (size_t)l * DI, yh, yl);
        // out_proj: (1568,1536) x (768,1536)^T -> hbuf (+ splits for next layer)
        mgemm_k<<<dim3(DD / 64, (M_ROWS + 127) / 128), 256, 0, stream>>>(
            yh, yl, woh, wol, hbuf, hbh, hbl, M_ROWS, DD, DI, nullptr, nullptr, 0);
    }

    ln_k<<<M_ROWS, 256, 0, stream>>>(hbuf, norm_w, norm_b, out);
}

// Round 4
// 3063.995 us; speedup vs baseline: 1.1744x; 1.1744x over previous
//
#include <hip/hip_runtime.h>

#define BB 8
#define IMG 224
#define DD 768
#define NLAY 12
#define DI 1536
#define DS 16
#define DTR 48
#define NPATCH 196
#define L_SEQ 196
#define M_ROWS 1568   // BB*NPATCH
#define DCONV 4
#define NC 14         // scan chunks
#define LC 14         // chunk length (NC*LC == L_SEQ)

typedef _Float16 f16x8 __attribute__((ext_vector_type(8)));
typedef _Float16 f16x4 __attribute__((ext_vector_type(4)));
typedef float f32x4 __attribute__((ext_vector_type(4)));

// ---------------- split fp32 -> (hi,lo) f16 planes, 4 elems/thread ----------------
__global__ __launch_bounds__(256) void split4_k(const float* __restrict__ in,
    _Float16* __restrict__ hi, _Float16* __restrict__ lo, int n4)
{
    int i = blockIdx.x * 256 + threadIdx.x;
    if (i >= n4) return;
    float4 v = ((const float4*)in)[i];
    _Float16 h0 = (_Float16)v.x, h1 = (_Float16)v.y, h2 = (_Float16)v.z, h3 = (_Float16)v.w;
    f16x4 H = {h0, h1, h2, h3};
    f16x4 L = {(_Float16)(v.x - (float)h0), (_Float16)(v.y - (float)h1),
               (_Float16)(v.z - (float)h2), (_Float16)(v.w - (float)h3)};
    ((f16x4*)hi)[i] = H;
    ((f16x4*)lo)[i] = L;
}

// ---------------- im2col with split output ----------------
__global__ __launch_bounds__(256) void im2col_k(const float* __restrict__ x,
    _Float16* __restrict__ hi, _Float16* __restrict__ lo)
{
    int idx = blockIdx.x * 256 + threadIdx.x;
    if (idx >= M_ROWS * DD) return;
    int k = idx % DD;
    int m = idx / DD;
    int b = m / NPATCH;
    int t = m % NPATCH;
    int i = t / 14, j = t % 14;
    int c = k / 256;
    int pq = k % 256;
    int p = pq / 16, q = pq % 16;
    float v = x[(((size_t)b * 3 + c) * IMG + i * 16 + p) * IMG + j * 16 + q];
    _Float16 h = (_Float16)v;
    hi[idx] = h;
    lo[idx] = (_Float16)(v - (float)h);
}

// ---------------- f16x3 MFMA GEMM: C[M,N] = (Ah+Al)[M,K] * (Bh+Bl)[N,K]^T ----------------
// mode 0: plain   mode 2: += bias[n] + pos[(m%196)*N+n]
// C (f32), Chi/Clo (f16 split) each optional (nullptr skips).
__global__ __launch_bounds__(256) void mgemm_k(
    const _Float16* __restrict__ Ah, const _Float16* __restrict__ Al,
    const _Float16* __restrict__ Bh, const _Float16* __restrict__ Bl,
    float* __restrict__ C, _Float16* __restrict__ Chi, _Float16* __restrict__ Clo,
    int M, int N, int K,
    const float* __restrict__ bias, const float* __restrict__ pos, int mode)
{
    __shared__ _Float16 As[2][128][40];
    __shared__ _Float16 Bs[2][64][40];
    int tid = threadIdx.x;
    int m0 = blockIdx.y * 128, n0 = blockIdx.x * 64;
    int lane = tid & 63;
    int wid = tid >> 6;
    int wM = (wid >> 1) * 64, wN = (wid & 1) * 32;
    int lm = lane & 15, quad = lane >> 4;

    f32x4 acc[4][2] = {};

    int apl = tid >> 7, arow = tid & 127;
    int bpl = tid >> 7, brow = (tid >> 1) & 63, bseg = tid & 1;
    const _Float16* Asrc = apl ? Al : Ah;
    const _Float16* Bsrc = bpl ? Bl : Bh;
    int gm = m0 + arow;
    int gn = n0 + brow;

    for (int k0 = 0; k0 < K; k0 += 32) {
        float4 av0 = make_float4(0.f,0.f,0.f,0.f), av1 = av0, av2 = av0, av3 = av0;
        if (gm < M) {
            const float4* p = (const float4*)&Asrc[(size_t)gm * K + k0];
            av0 = p[0]; av1 = p[1]; av2 = p[2]; av3 = p[3];
        }
        const float4* q = (const float4*)&Bsrc[(size_t)gn * K + k0 + bseg * 16];
        float4 bv0 = q[0], bv1 = q[1];
        *(float4*)&As[apl][arow][0]  = av0;
        *(float4*)&As[apl][arow][8]  = av1;
        *(float4*)&As[apl][arow][16] = av2;
        *(float4*)&As[apl][arow][24] = av3;
        *(float4*)&Bs[bpl][brow][bseg * 16]     = bv0;
        *(float4*)&Bs[bpl][brow][bseg * 16 + 8] = bv1;
        __syncthreads();

        f16x8 a_h[4], a_l[4], b_h[2], b_l[2];
#pragma unroll
        for (int mi = 0; mi < 4; ++mi) {
            a_h[mi] = *(const f16x8*)&As[0][wM + mi * 16 + lm][quad * 8];
            a_l[mi] = *(const f16x8*)&As[1][wM + mi * 16 + lm][quad * 8];
        }
#pragma unroll
        for (int ni = 0; ni < 2; ++ni) {
            b_h[ni] = *(const f16x8*)&Bs[0][wN + ni * 16 + lm][quad * 8];
            b_l[ni] = *(const f16x8*)&Bs[1][wN + ni * 16 + lm][quad * 8];
        }
#pragma unroll
        for (int mi = 0; mi < 4; ++mi)
#pragma unroll
            for (int ni = 0; ni < 2; ++ni) {
                acc[mi][ni] = __builtin_amdgcn_mfma_f32_16x16x32_f16(a_h[mi], b_h[ni], acc[mi][ni], 0, 0, 0);
                acc[mi][ni] = __builtin_amdgcn_mfma_f32_16x16x32_f16(a_h[mi], b_l[ni], acc[mi][ni], 0, 0, 0);
                acc[mi][ni] = __builtin_amdgcn_mfma_f32_16x16x32_f16(a_l[mi], b_h[ni], acc[mi][ni], 0, 0, 0);
            }
        __syncthreads();
    }

#pragma unroll
    for (int mi = 0; mi < 4; ++mi)
#pragma unroll
        for (int ni = 0; ni < 2; ++ni)
#pragma unroll
            for (int r = 0; r < 4; ++r) {
                int row = m0 + wM + mi * 16 + quad * 4 + r;
                if (row >= M) continue;
                int col = n0 + wN + ni * 16 + lm;
                float v = acc[mi][ni][r];
                if (mode == 2) v += bias[col] + pos[(size_t)(row % NPATCH) * N + col];
                size_t idx = (size_t)row * N + col;
                if (C) C[idx] = v;
                if (Chi) {
                    _Float16 h = (_Float16)v;
                    Chi[idx] = h;
                    Clo[idx] = (_Float16)(v - (float)h);
                }
            }
}

// ---------------- generic tiled fp32 GEMM (x_proj / dt_proj) ----------------
// mode 1: softplus(acc + bias[n])    mode 3: atomicAdd (split-K over gridDim.z)
__global__ __launch_bounds__(256) void gemm_k(
    const float* __restrict__ A, int lda,
    const float* __restrict__ Bw,
    float* __restrict__ C,
    int M, int N, int K,
    const float* __restrict__ bias,
    int mode)
{
    __shared__ __align__(16) float As[16][68];
    __shared__ __align__(16) float Bs[16][68];
    int tid = threadIdx.x;
    int m0 = blockIdx.y * 64;
    int n0 = blockIdx.x * 64;
    int tx = tid & 15;
    int ty = tid >> 4;
    float acc[4][4] = {};
    int lrow = tid >> 2;
    int lk4  = (tid & 3) << 2;
    int kPer = K / gridDim.z;
    int kBeg = blockIdx.z * kPer;
    for (int k0 = kBeg; k0 < kBeg + kPer; k0 += 16) {
        {
            int m = m0 + lrow;
            float4 va = make_float4(0.f, 0.f, 0.f, 0.f);
            if (m < M) va = *(const float4*)&A[(size_t)m * lda + k0 + lk4];
            As[lk4 + 0][lrow] = va.x; As[lk4 + 1][lrow] = va.y;
            As[lk4 + 2][lrow] = va.z; As[lk4 + 3][lrow] = va.w;
        }
        {
            int n = n0 + lrow;
            float4 vb = make_float4(0.f, 0.f, 0.f, 0.f);
            if (n < N) vb = *(const float4*)&Bw[(size_t)n * K + k0 + lk4];
            Bs[lk4 + 0][lrow] = vb.x; Bs[lk4 + 1][lrow] = vb.y;
            Bs[lk4 + 2][lrow] = vb.z; Bs[lk4 + 3][lrow] = vb.w;
        }
        __syncthreads();
#pragma unroll
        for (int kk = 0; kk < 16; ++kk) {
            float4 a4 = *(const float4*)&As[kk][ty * 4];
            float4 b4 = *(const float4*)&Bs[kk][tx * 4];
            float av[4] = {a4.x, a4.y, a4.z, a4.w};
            float bv[4] = {b4.x, b4.y, b4.z, b4.w};
#pragma unroll
            for (int i = 0; i < 4; ++i)
#pragma unroll
                for (int j = 0; j < 4; ++j)
                    acc[i][j] += av[i] * bv[j];
        }
        __syncthreads();
    }
#pragma unroll
    for (int i = 0; i < 4; ++i) {
        int m = m0 + ty * 4 + i;
        if (m >= M) continue;
#pragma unroll
        for (int j = 0; j < 4; ++j) {
            int n = n0 + tx * 4 + j;
            if (n >= N) continue;
            float v = acc[i][j];
            if (mode == 1) {
                v += bias[n];
                v = (v > 20.f) ? v : log1pf(__expf(v));
            }
            if (mode == 3) atomicAdd(&C[(size_t)m * N + n], v);
            else           C[(size_t)m * N + n] = v;
        }
    }
}

// ---------------- causal depthwise conv (k=4) + SiLU ----------------
__global__ __launch_bounds__(256) void conv_k(
    const float* __restrict__ xz, const float* __restrict__ cw,
    const float* __restrict__ cb, float* __restrict__ xc)
{
    int idx = blockIdx.x * 256 + threadIdx.x;
    if (idx >= M_ROWS * DI) return;
    int e = idx % DI;
    int m = idx / DI;
    int l = m % L_SEQ;
    float acc = cb[e];
#pragma unroll
    for (int k = 0; k < DCONV; ++k) {
        int ls = l + k - (DCONV - 1);
        if (ls >= 0) acc += cw[e * DCONV + k] * xz[(size_t)(m + k - (DCONV - 1)) * (2 * DI) + e];
    }
    xc[idx] = acc / (1.f + __expf(-acc));
}

// ================= chunked selective scan (3 passes) =================
// Thread per (b,d) [passes A,C additionally per chunk]; 16 states in regs.
// h_{l} = exp(dt_l*A[s]) * h_{l-1} + dt_l*x_l*B_l[s]; chunk transition factor
// for a whole chunk is exp(A[s] * sum(dt)) (closed form).

// Pass A: per-chunk scan from h=0 -> hpart[(b,c,s),d], Sdt[(b,c),d]
__global__ __launch_bounds__(64) void scanA_k(
    const float* __restrict__ dt, const float* __restrict__ xc,
    const float* __restrict__ proj, const float* __restrict__ A_log,
    float* __restrict__ hpart, float* __restrict__ Sdt)
{
    int d = blockIdx.x * 64 + threadIdx.x;
    int b = blockIdx.y, c = blockIdx.z;
    float Aa[DS];
#pragma unroll
    for (int s = 0; s < DS; ++s) Aa[s] = -__expf(A_log[d * DS + s]);
    float h[DS];
#pragma unroll
    for (int s = 0; s < DS; ++s) h[s] = 0.f;
    float sdt = 0.f;
    size_t base = (size_t)b * L_SEQ + c * LC;
#pragma unroll 2
    for (int l = 0; l < LC; ++l) {
        float dtv = dt[(base + l) * DI + d];
        float xv  = xc[(base + l) * DI + d];
        const float* pr = proj + (base + l) * 80;
        float dx = dtv * xv;
        sdt += dtv;
#pragma unroll
        for (int s = 0; s < DS; ++s)
            h[s] = __expf(dtv * Aa[s]) * h[s] + dx * pr[DTR + s];
    }
    size_t o = (size_t)(b * NC + c) * DS * DI + d;
#pragma unroll
    for (int s = 0; s < DS; ++s) hpart[o + (size_t)s * DI] = h[s];
    Sdt[(size_t)(b * NC + c) * DI + d] = sdt;
}

// Pass B: compose chunk-initial states h0[(b,c,s),d]
__global__ __launch_bounds__(64) void scanB_k(
    const float* __restrict__ A_log, const float* __restrict__ hpart,
    const float* __restrict__ Sdt, float* __restrict__ h0)
{
    int d = blockIdx.x * 64 + threadIdx.x;
    int b = blockIdx.y;
    float Aa[DS];
#pragma unroll
    for (int s = 0; s < DS; ++s) Aa[s] = -__expf(A_log[d * DS + s]);
    float h[DS];
#pragma unroll
    for (int s = 0; s < DS; ++s) h[s] = 0.f;
    for (int c = 0; c < NC; ++c) {
        size_t o = (size_t)(b * NC + c) * DS * DI + d;
#pragma unroll
        for (int s = 0; s < DS; ++s) h0[o + (size_t)s * DI] = h[s];
        float sdt = Sdt[(size_t)(b * NC + c) * DI + d];
#pragma unroll
        for (int s = 0; s < DS; ++s)
            h[s] = __expf(Aa[s] * sdt) * h[s] + hpart[o + (size_t)s * DI];
    }
}

// Pass C: replay chunk from its true h0, emit gated y (f16 hi/lo split)
__global__ __launch_bounds__(64) void scanC_k(
    const float* __restrict__ dt, const float* __restrict__ xc,
    const float* __restrict__ proj, const float* __restrict__ xz,
    const float* __restrict__ A_log, const float* __restrict__ Dp,
    const float* __restrict__ h0,
    _Float16* __restrict__ yh, _Float16* __restrict__ yl)
{
    int d = blockIdx.x * 64 + threadIdx.x;
    int b = blockIdx.y, c = blockIdx.z;
    float Aa[DS];
#pragma unroll
    for (int s = 0; s < DS; ++s) Aa[s] = -__expf(A_log[d * DS + s]);
    float h[DS];
    size_t o = (size_t)(b * NC + c) * DS * DI + d;
#pragma unroll
    for (int s = 0; s < DS; ++s) h[s] = h0[o + (size_t)s * DI];
    float dP = Dp[d];
    size_t base = (size_t)b * L_SEQ + c * LC;
#pragma unroll 2
    for (int l = 0; l < LC; ++l) {
        float dtv = dt[(base + l) * DI + d];
        float xv  = xc[(base + l) * DI + d];
        float zv  = xz[(base + l) * 2 * DI + DI + d];
        const float* pr = proj + (base + l) * 80;
        float dx = dtv * xv;
        float accv = 0.f;
#pragma unroll
        for (int s = 0; s < DS; ++s) {
            h[s] = __expf(dtv * Aa[s]) * h[s] + dx * pr[DTR + s];
            accv += h[s] * pr[DTR + DS + s];
        }
        float yv = accv + xv * dP;
        float sg = 1.f / (1.f + __expf(-zv));
        float vy = yv * (zv * sg);
        size_t oidx = (base + l) * DI + d;
        _Float16 hh = (_Float16)vy;
        yh[oidx] = hh;
        yl[oidx] = (_Float16)(vy - (float)hh);
    }
}

// ---------------- layernorm over D=768, input reconstructed from f16 hi+lo ----------------
__global__ __launch_bounds__(256) void ln_k(const _Float16* __restrict__ hh,
    const _Float16* __restrict__ hl,
    const float* __restrict__ w, const float* __restrict__ bias, float* __restrict__ out)
{
    int row = blockIdx.x;
    int tid = threadIdx.x;
    size_t base = (size_t)row * DD;
    float v0 = (float)hh[base + tid]       + (float)hl[base + tid];
    float v1 = (float)hh[base + tid + 256] + (float)hl[base + tid + 256];
    float v2 = (float)hh[base + tid + 512] + (float)hl[base + tid + 512];
    float s = v0 + v1 + v2;
    __shared__ float red[4];
    for (int off = 32; off; off >>= 1) s += __shfl_down(s, off);
    if ((tid & 63) == 0) red[tid >> 6] = s;
    __syncthreads();
    float mu = (red[0] + red[1] + red[2] + red[3]) * (1.f / 768.f);
    __syncthreads();
    float d0 = v0 - mu, d1 = v1 - mu, d2 = v2 - mu;
    float vs = d0 * d0 + d1 * d1 + d2 * d2;
    for (int off = 32; off; off >>= 1) vs += __shfl_down(vs, off);
    if ((tid & 63) == 0) red[tid >> 6] = vs;
    __syncthreads();
    float var = (red[0] + red[1] + red[2] + red[3]) * (1.f / 768.f);
    float rs = rsqrtf(var + 1e-5f);
    out[base + tid]       = d0 * rs * w[tid]       + bias[tid];
    out[base + tid + 256] = d1 * rs * w[tid + 256] + bias[tid + 256];
    out[base + tid + 512] = d2 * rs * w[tid + 512] + bias[tid + 512];
}

__global__ __launch_bounds__(256) void fill0_k(float* __restrict__ p, int n) {
    int i = blockIdx.x * 256 + threadIdx.x;
    if (i < n) p[i] = 0.f;
}

extern "C" void kernel_launch(void* const* d_in, const int* in_sizes, int n_in,
                              void* d_out, int out_size, void* d_ws, size_t ws_size,
                              hipStream_t stream) {
    const float* x        = (const float*)d_in[0];
    const float* patch_w  = (const float*)d_in[1];
    const float* patch_b  = (const float*)d_in[2];
    const float* pos      = (const float*)d_in[3];
    const float* in_proj  = (const float*)d_in[4];
    const float* conv_w   = (const float*)d_in[5];
    const float* conv_b   = (const float*)d_in[6];
    const float* x_proj   = (const float*)d_in[7];
    const float* dt_w     = (const float*)d_in[8];
    const float* dt_b     = (const float*)d_in[9];
    const float* A_log    = (const float*)d_in[10];
    const float* D_param  = (const float*)d_in[11];
    const float* out_w    = (const float*)d_in[12];
    const float* norm_w   = (const float*)d_in[13];
    const float* norm_b   = (const float*)d_in[14];
    float* out = (float*)d_out;

    // fp32 workspace
    float* ws    = (float*)d_ws;
    float* xzb   = ws;                      // 4,816,896
    float* xcb   = xzb   + 4816896;         // 2,408,448
    float* projb = xcb   + 2408448;         //   125,440
    float* dtb   = projb + 125440;          // 2,408,448
    float* hpart = dtb   + 2408448;         // 2,752,512  (BB*NC*DS*DI)
    float* h0b   = hpart + 2752512;         // 2,752,512
    float* sdtb  = h0b   + 2752512;         //   172,032  (BB*NC*DI)
    // f16 split workspace
    _Float16* h16 = (_Float16*)(sdtb + 172032);
    _Float16* hbh = h16;                    // 1,204,224
    _Float16* hbl = hbh + 1204224;          // 1,204,224
    _Float16* yh  = hbl + 1204224;          // 2,408,448 (also im2col hi at start)
    _Float16* yl  = yh  + 2408448;          // 2,408,448
    _Float16* pwh = yl  + 2408448;          //   589,824
    _Float16* pwl = pwh + 589824;
    _Float16* wih = pwl + 589824;           // 2,359,296 (per-layer in_proj_w split)
    _Float16* wil = wih + 2359296;
    _Float16* woh = wil + 2359296;          // 1,179,648 (per-layer out_proj_w split)
    _Float16* wol = woh + 1179648;

    // patch embed
    split4_k<<<(589824 / 4 + 255) / 256, 256, 0, stream>>>(patch_w, pwh, pwl, 589824 / 4);
    im2col_k<<<(M_ROWS * DD + 255) / 256, 256, 0, stream>>>(x, yh, yl);
    mgemm_k<<<dim3(DD / 64, (M_ROWS + 127) / 128), 256, 0, stream>>>(
        yh, yl, pwh, pwl, nullptr, hbh, hbl, M_ROWS, DD, DD, patch_b, pos, 2);

    for (int l = 0; l < NLAY; ++l) {
        const float* Al = A_log + (size_t)l * DI * DS;
        split4_k<<<(2359296 / 4 + 255) / 256, 256, 0, stream>>>(
            in_proj + (size_t)l * 2 * DI * DD, wih, wil, 2359296 / 4);
        split4_k<<<(1179648 / 4 + 255) / 256, 256, 0, stream>>>(
            out_w + (size_t)l * DD * DI, woh, wol, 1179648 / 4);
        // in_proj -> xz (fp32)
        mgemm_k<<<dim3(2 * DI / 64, (M_ROWS + 127) / 128), 256, 0, stream>>>(
            hbh, hbl, wih, wil, xzb, nullptr, nullptr, M_ROWS, 2 * DI, DD, nullptr, nullptr, 0);
        // causal conv + silu -> xc
        conv_k<<<(M_ROWS * DI) / 256, 256, 0, stream>>>(xzb, conv_w + (size_t)l * DI * DCONV,
                                                        conv_b + (size_t)l * DI, xcb);
        // x_proj (N=80): split-K=4 atomicAdd
        fill0_k<<<(M_ROWS * 80 + 255) / 256, 256, 0, stream>>>(projb, M_ROWS * 80);
        gemm_k<<<dim3(2, 25, 4), 256, 0, stream>>>(xcb, DI, x_proj + (size_t)l * 80 * DI, projb,
                                                   M_ROWS, 80, DI, nullptr, 3);
        // dt_proj + softplus
        gemm_k<<<dim3(24, 25), 256, 0, stream>>>(projb, 80, dt_w + (size_t)l * DI * DTR, dtb,
                                                 M_ROWS, DI, DTR, dt_b + (size_t)l * DI, 1);
        // chunked scan
        scanA_k<<<dim3(DI / 64, BB, NC), 64, 0, stream>>>(dtb, xcb, projb, Al, hpart, sdtb);
        scanB_k<<<dim3(DI / 64, BB), 64, 0, stream>>>(Al, hpart, sdtb, h0b);
        scanC_k<<<dim3(DI / 64, BB, NC), 64, 0, stream>>>(dtb, xcb, projb, xzb, Al,
                                                          D_param + (size_t)l * DI, h0b, yh, yl);
        // out_proj -> h splits
        mgemm_k<<<dim3(DD / 64, (M_ROWS + 127) / 128), 256, 0, stream>>>(
            yh, yl, woh, wol, nullptr, hbh, hbl, M_ROWS, DD, DI, nullptr, nullptr, 0);
    }

    ln_k<<<M_ROWS, 256, 0, stream>>>(hbh, hbl, norm_w, norm_b, out);
}

// Round 5
// 2382.708 us; speedup vs baseline: 1.5102x; 1.2859x over previous
//
#include <hip/hip_runtime.h>

#define BB 8
#define IMG 224
#define DD 768
#define NLAY 12
#define DI 1536
#define DS 16
#define DTR 48
#define NPATCH 196
#define L_SEQ 196
#define M_ROWS 1568   // BB*NPATCH
#define DCONV 4
#define NC 14         // scan chunks
#define LC 14         // chunk length

typedef _Float16 f16x8 __attribute__((ext_vector_type(8)));
typedef _Float16 f16x4 __attribute__((ext_vector_type(4)));
typedef float f32x4 __attribute__((ext_vector_type(4)));

// async 16B global -> LDS (lane i writes lds_base + i*16)
__device__ __forceinline__ void gll16(const void* g, void* l) {
    __builtin_amdgcn_global_load_lds(
        (const __attribute__((address_space(1))) unsigned int*)g,
        (__attribute__((address_space(3))) unsigned int*)l,
        16, 0, 0);
}

// ---------------- split fp32 -> (hi,lo) f16 planes, 4 elems/thread ----------------
__global__ __launch_bounds__(256) void split4_k(const float* __restrict__ in,
    _Float16* __restrict__ hi, _Float16* __restrict__ lo, int n4)
{
    int i = blockIdx.x * 256 + threadIdx.x;
    if (i >= n4) return;
    float4 v = ((const float4*)in)[i];
    _Float16 h0 = (_Float16)v.x, h1 = (_Float16)v.y, h2 = (_Float16)v.z, h3 = (_Float16)v.w;
    f16x4 H = {h0, h1, h2, h3};
    f16x4 L = {(_Float16)(v.x - (float)h0), (_Float16)(v.y - (float)h1),
               (_Float16)(v.z - (float)h2), (_Float16)(v.w - (float)h3)};
    ((f16x4*)hi)[i] = H;
    ((f16x4*)lo)[i] = L;
}

// ---------------- split with zero-padding (rows/cols), scalar ----------------
__global__ __launch_bounds__(256) void splitpad_k(const float* __restrict__ in,
    _Float16* __restrict__ hi, _Float16* __restrict__ lo,
    int inRows, int inCols, int inLd, int outLd, int total)
{
    int i = blockIdx.x * 256 + threadIdx.x;
    if (i >= total) return;
    int r = i / outLd, c = i % outLd;
    float v = (r < inRows && c < inCols) ? in[(size_t)r * inLd + c] : 0.f;
    _Float16 h = (_Float16)v;
    hi[i] = h;
    lo[i] = (_Float16)(v - (float)h);
}

// ---------------- im2col with split output ----------------
__global__ __launch_bounds__(256) void im2col_k(const float* __restrict__ x,
    _Float16* __restrict__ hi, _Float16* __restrict__ lo)
{
    int idx = blockIdx.x * 256 + threadIdx.x;
    if (idx >= M_ROWS * DD) return;
    int k = idx % DD;
    int m = idx / DD;
    int b = m / NPATCH;
    int t = m % NPATCH;
    int i = t / 14, j = t % 14;
    int c = k / 256;
    int pq = k % 256;
    int p = pq / 16, q = pq % 16;
    float v = x[(((size_t)b * 3 + c) * IMG + i * 16 + p) * IMG + j * 16 + q];
    _Float16 h = (_Float16)v;
    hi[idx] = h;
    lo[idx] = (_Float16)(v - (float)h);
}

// ---------------- f16x3 MFMA GEMM, 64x64x32 tiles, global_load_lds + double buffer ----------------
// C[M,N] = (Ah+Al)[M,K(lda)] * (Bh+Bl)[N,K]^T
// mode 0: plain  1: softplus(v+bias[n])  2: v+bias[n]+pos[(m%196)*N+n]  3: atomicAdd (split-K over grid.z)
// C (f32) and Chi/Clo (f16 split) each optional. Store masked to row<M, col<Nstore.
// A buffers must be padded to ceil(M/64)*64 rows (garbage OK); B to ceil over 64 rows.
__global__ __launch_bounds__(256) void mgemm_k(
    const _Float16* __restrict__ Ah, const _Float16* __restrict__ Al,
    const _Float16* __restrict__ Bh, const _Float16* __restrict__ Bl,
    float* __restrict__ C, _Float16* __restrict__ Chi, _Float16* __restrict__ Clo,
    int M, int N, int K, int lda, int Nstore,
    const float* __restrict__ bias, const float* __restrict__ pos, int mode)
{
    __shared__ __align__(16) _Float16 As[2][2][64][32];   // [buf][plane][m][k]
    __shared__ __align__(16) _Float16 Bs[2][2][64][32];
    int tid = threadIdx.x, lane = tid & 63, wid = tid >> 6;
    int m0 = blockIdx.y * 64, n0 = blockIdx.x * 64;
    int kBeg = 0, nIter = K / 32;
    if (gridDim.z > 1) { int kPer = K / gridDim.z; kBeg = blockIdx.z * kPer; nIter = kPer / 32; }

    // staging map: wave wid covers 16 rows; lane i -> row wid*16 + i/4, col (i%4)*8
    int srow = wid * 16 + (lane >> 2);
    int scol = (lane & 3) * 8;
    const _Float16* aH = Ah + (size_t)(m0 + srow) * lda + kBeg + scol;
    const _Float16* aL = Al + (size_t)(m0 + srow) * lda + kBeg + scol;
    const _Float16* bH = Bh + (size_t)(n0 + srow) * K + kBeg + scol;
    const _Float16* bL = Bl + (size_t)(n0 + srow) * K + kBeg + scol;

#define STAGE(buf, it) { int ko = (it) * 32;              \
        gll16(aH + ko, &As[buf][0][wid * 16][0]);          \
        gll16(aL + ko, &As[buf][1][wid * 16][0]);          \
        gll16(bH + ko, &Bs[buf][0][wid * 16][0]);          \
        gll16(bL + ko, &Bs[buf][1][wid * 16][0]); }

    int wm = (wid >> 1) * 32, wn = (wid & 1) * 32;
    int lm = lane & 15, quad = lane >> 4;
    f32x4 acc[2][2] = {};

    STAGE(0, 0);
    for (int it = 0; it < nIter; ++it) {
        int buf = it & 1;
        if (it + 1 < nIter) STAGE(buf ^ 1, it + 1);
        __syncthreads();
        f16x8 ah[2], al2[2], bh2[2], bl2[2];
#pragma unroll
        for (int i = 0; i < 2; ++i) {
            ah[i]  = *(const f16x8*)&As[buf][0][wm + i * 16 + lm][quad * 8];
            al2[i] = *(const f16x8*)&As[buf][1][wm + i * 16 + lm][quad * 8];
            bh2[i] = *(const f16x8*)&Bs[buf][0][wn + i * 16 + lm][quad * 8];
            bl2[i] = *(const f16x8*)&Bs[buf][1][wn + i * 16 + lm][quad * 8];
        }
#pragma unroll
        for (int mi = 0; mi < 2; ++mi)
#pragma unroll
            for (int ni = 0; ni < 2; ++ni) {
                acc[mi][ni] = __builtin_amdgcn_mfma_f32_16x16x32_f16(ah[mi],  bh2[ni], acc[mi][ni], 0, 0, 0);
                acc[mi][ni] = __builtin_amdgcn_mfma_f32_16x16x32_f16(ah[mi],  bl2[ni], acc[mi][ni], 0, 0, 0);
                acc[mi][ni] = __builtin_amdgcn_mfma_f32_16x16x32_f16(al2[mi], bh2[ni], acc[mi][ni], 0, 0, 0);
            }
        __syncthreads();
    }
#undef STAGE

#pragma unroll
    for (int mi = 0; mi < 2; ++mi)
#pragma unroll
        for (int ni = 0; ni < 2; ++ni)
#pragma unroll
            for (int r = 0; r < 4; ++r) {
                int row = m0 + wm + mi * 16 + quad * 4 + r;
                int col = n0 + wn + ni * 16 + lm;
                if (row >= M || col >= Nstore) continue;
                float v = acc[mi][ni][r];
                if (mode == 1) { v += bias[col]; v = (v > 20.f) ? v : log1pf(__expf(v)); }
                else if (mode == 2) v += bias[col] + pos[(size_t)(row % NPATCH) * N + col];
                size_t idx = (size_t)row * N + col;
                if (mode == 3) { atomicAdd(&C[idx], v); continue; }
                if (C) C[idx] = v;
                if (Chi) {
                    _Float16 h = (_Float16)v;
                    Chi[idx] = h;
                    Clo[idx] = (_Float16)(v - (float)h);
                }
            }
}

// ---------------- causal depthwise conv (k=4) + SiLU -> f16 split ----------------
__global__ __launch_bounds__(256) void conv_k(
    const float* __restrict__ xz, const float* __restrict__ cw,
    const float* __restrict__ cb, _Float16* __restrict__ xch, _Float16* __restrict__ xcl)
{
    int idx = blockIdx.x * 256 + threadIdx.x;
    if (idx >= M_ROWS * DI) return;
    int e = idx % DI;
    int m = idx / DI;
    int l = m % L_SEQ;
    float acc = cb[e];
#pragma unroll
    for (int k = 0; k < DCONV; ++k) {
        int ls = l + k - (DCONV - 1);
        if (ls >= 0) acc += cw[e * DCONV + k] * xz[(size_t)(m + k - (DCONV - 1)) * (2 * DI) + e];
    }
    float v = acc / (1.f + __expf(-acc));
    _Float16 h = (_Float16)v;
    xch[idx] = h;
    xcl[idx] = (_Float16)(v - (float)h);
}

// ================= chunked selective scan (3 passes) =================
__global__ __launch_bounds__(64) void scanA_k(
    const _Float16* __restrict__ doh, const _Float16* __restrict__ dol,
    const _Float16* __restrict__ xch, const _Float16* __restrict__ xcl,
    const float* __restrict__ proj, const float* __restrict__ A_log,
    float* __restrict__ hpart, float* __restrict__ Sdt)
{
    int d = blockIdx.x * 64 + threadIdx.x;
    int b = blockIdx.y, c = blockIdx.z;
    float Aa[DS];
#pragma unroll
    for (int s = 0; s < DS; ++s) Aa[s] = -__expf(A_log[d * DS + s]);
    float h[DS];
#pragma unroll
    for (int s = 0; s < DS; ++s) h[s] = 0.f;
    float sdt = 0.f;
    size_t base = (size_t)b * L_SEQ + c * LC;
#pragma unroll 2
    for (int l = 0; l < LC; ++l) {
        size_t ii = (base + l) * DI + d;
        float dtv = (float)doh[ii] + (float)dol[ii];
        float xv  = (float)xch[ii] + (float)xcl[ii];
        const float* pr = proj + (base + l) * 80;
        float dx = dtv * xv;
        sdt += dtv;
#pragma unroll
        for (int s = 0; s < DS; ++s)
            h[s] = __expf(dtv * Aa[s]) * h[s] + dx * pr[DTR + s];
    }
    size_t o = (size_t)(b * NC + c) * DS * DI + d;
#pragma unroll
    for (int s = 0; s < DS; ++s) hpart[o + (size_t)s * DI] = h[s];
    Sdt[(size_t)(b * NC + c) * DI + d] = sdt;
}

__global__ __launch_bounds__(64) void scanB_k(
    const float* __restrict__ A_log, const float* __restrict__ hpart,
    const float* __restrict__ Sdt, float* __restrict__ h0)
{
    int d = blockIdx.x * 64 + threadIdx.x;
    int b = blockIdx.y;
    float Aa[DS];
#pragma unroll
    for (int s = 0; s < DS; ++s) Aa[s] = -__expf(A_log[d * DS + s]);
    float h[DS];
#pragma unroll
    for (int s = 0; s < DS; ++s) h[s] = 0.f;
    for (int c = 0; c < NC; ++c) {
        size_t o = (size_t)(b * NC + c) * DS * DI + d;
#pragma unroll
        for (int s = 0; s < DS; ++s) h0[o + (size_t)s * DI] = h[s];
        float sdt = Sdt[(size_t)(b * NC + c) * DI + d];
#pragma unroll
        for (int s = 0; s < DS; ++s)
            h[s] = __expf(Aa[s] * sdt) * h[s] + hpart[o + (size_t)s * DI];
    }
}

__global__ __launch_bounds__(64) void scanC_k(
    const _Float16* __restrict__ doh, const _Float16* __restrict__ dol,
    const _Float16* __restrict__ xch, const _Float16* __restrict__ xcl,
    const float* __restrict__ proj, const float* __restrict__ xz,
    const float* __restrict__ A_log, const float* __restrict__ Dp,
    const float* __restrict__ h0,
    _Float16* __restrict__ yh, _Float16* __restrict__ yl)
{
    int d = blockIdx.x * 64 + threadIdx.x;
    int b = blockIdx.y, c = blockIdx.z;
    float Aa[DS];
#pragma unroll
    for (int s = 0; s < DS; ++s) Aa[s] = -__expf(A_log[d * DS + s]);
    float h[DS];
    size_t o = (size_t)(b * NC + c) * DS * DI + d;
#pragma unroll
    for (int s = 0; s < DS; ++s) h[s] = h0[o + (size_t)s * DI];
    float dP = Dp[d];
    size_t base = (size_t)b * L_SEQ + c * LC;
#pragma unroll 2
    for (int l = 0; l < LC; ++l) {
        size_t ii = (base + l) * DI + d;
        float dtv = (float)doh[ii] + (float)dol[ii];
        float xv  = (float)xch[ii] + (float)xcl[ii];
        float zv  = xz[(base + l) * 2 * DI + DI + d];
        const float* pr = proj + (base + l) * 80;
        float dx = dtv * xv;
        float accv = 0.f;
#pragma unroll
        for (int s = 0; s < DS; ++s) {
            h[s] = __expf(dtv * Aa[s]) * h[s] + dx * pr[DTR + s];
            accv += h[s] * pr[DTR + DS + s];
        }
        float yv = accv + xv * dP;
        float sg = 1.f / (1.f + __expf(-zv));
        float vy = yv * (zv * sg);
        _Float16 hh = (_Float16)vy;
        yh[ii] = hh;
        yl[ii] = (_Float16)(vy - (float)hh);
    }
}

// ---------------- layernorm over D=768 from f16 hi+lo ----------------
__global__ __launch_bounds__(256) void ln_k(const _Float16* __restrict__ hh,
    const _Float16* __restrict__ hl,
    const float* __restrict__ w, const float* __restrict__ bias, float* __restrict__ out)
{
    int row = blockIdx.x;
    int tid = threadIdx.x;
    size_t base = (size_t)row * DD;
    float v0 = (float)hh[base + tid]       + (float)hl[base + tid];
    float v1 = (float)hh[base + tid + 256] + (float)hl[base + tid + 256];
    float v2 = (float)hh[base + tid + 512] + (float)hl[base + tid + 512];
    float s = v0 + v1 + v2;
    __shared__ float red[4];
    for (int off = 32; off; off >>= 1) s += __shfl_down(s, off);
    if ((tid & 63) == 0) red[tid >> 6] = s;
    __syncthreads();
    float mu = (red[0] + red[1] + red[2] + red[3]) * (1.f / 768.f);
    __syncthreads();
    float d0 = v0 - mu, d1 = v1 - mu, d2 = v2 - mu;
    float vs = d0 * d0 + d1 * d1 + d2 * d2;
    for (int off = 32; off; off >>= 1) vs += __shfl_down(vs, off);
    if ((tid & 63) == 0) red[tid >> 6] = vs;
    __syncthreads();
    float var = (red[0] + red[1] + red[2] + red[3]) * (1.f / 768.f);
    float rs = rsqrtf(var + 1e-5f);
    out[base + tid]       = d0 * rs * w[tid]       + bias[tid];
    out[base + tid + 256] = d1 * rs * w[tid + 256] + bias[tid + 256];
    out[base + tid + 512] = d2 * rs * w[tid + 512] + bias[tid + 512];
}

__global__ __launch_bounds__(256) void fill0_k(float* __restrict__ p, int n) {
    int i = blockIdx.x * 256 + threadIdx.x;
    if (i < n) p[i] = 0.f;
}

extern "C" void kernel_launch(void* const* d_in, const int* in_sizes, int n_in,
                              void* d_out, int out_size, void* d_ws, size_t ws_size,
                              hipStream_t stream) {
    const float* x        = (const float*)d_in[0];
    const float* patch_w  = (const float*)d_in[1];
    const float* patch_b  = (const float*)d_in[2];
    const float* pos      = (const float*)d_in[3];
    const float* in_proj  = (const float*)d_in[4];
    const float* conv_w   = (const float*)d_in[5];
    const float* conv_b   = (const float*)d_in[6];
    const float* x_proj   = (const float*)d_in[7];
    const float* dt_w     = (const float*)d_in[8];
    const float* dt_b     = (const float*)d_in[9];
    const float* A_log    = (const float*)d_in[10];
    const float* D_param  = (const float*)d_in[11];
    const float* out_w    = (const float*)d_in[12];
    const float* norm_w   = (const float*)d_in[13];
    const float* norm_b   = (const float*)d_in[14];
    float* out = (float*)d_out;

    // fp32 workspace
    float* ws    = (float*)d_ws;
    float* xzb   = ws;                      // 4,816,896
    float* projb = xzb   + 4816896;         //   125,440
    float* hpart = projb + 125440;          // 2,752,512
    float* h0b   = hpart + 2752512;         // 2,752,512
    float* sdtb  = h0b   + 2752512;         //   172,032
    // f16 split workspace (A-buffers padded to 1600 rows for global_load_lds)
    _Float16* fp  = (_Float16*)(sdtb + 172032);
    _Float16* hbh = fp;                     // 1600*768  = 1,228,800
    _Float16* hbl = hbh + 1228800;
    _Float16* yh  = hbl + 1228800;          // 1600*1536 = 2,457,600 (also im2col out)
    _Float16* yl  = yh  + 2457600;
    _Float16* xch = yl  + 2457600;          // 1600*1536
    _Float16* xcl = xch + 2457600;
    _Float16* doh = xcl + 2457600;          // 1568*1536 = 2,408,448 (dt_proj split out)
    _Float16* dol = doh + 2408448;
    _Float16* dih = dol + 2408448;          // 1600*64 = 102,400 (dt_proj input, K-padded)
    _Float16* dil = dih + 102400;
    _Float16* wih = dil + 102400;           // 3072*768 = 2,359,296
    _Float16* wil = wih + 2359296;
    _Float16* woh = wil + 2359296;          // 768*1536 = 1,179,648
    _Float16* wol = woh + 1179648;
    _Float16* xwh = wol + 1179648;          // 128*1536 = 196,608 (row-padded)
    _Float16* xwl = xwh + 196608;
    _Float16* dwh = xwl + 196608;           // 1536*64 = 98,304 (K-padded)
    _Float16* dwl = dwh + 98304;

    // ---- patch embed (reuse wih/wil for patch_w split; runs before layer loop) ----
    split4_k<<<(589824 / 4 + 255) / 256, 256, 0, stream>>>(patch_w, wih, wil, 589824 / 4);
    im2col_k<<<(M_ROWS * DD + 255) / 256, 256, 0, stream>>>(x, yh, yl);
    mgemm_k<<<dim3(12, 25), 256, 0, stream>>>(yh, yl, wih, wil,
        nullptr, hbh, hbl, M_ROWS, DD, DD, DD, DD, patch_b, pos, 2);

    for (int l = 0; l < NLAY; ++l) {
        const float* Al = A_log + (size_t)l * DI * DS;
        split4_k<<<(2359296 / 4 + 255) / 256, 256, 0, stream>>>(
            in_proj + (size_t)l * 2 * DI * DD, wih, wil, 2359296 / 4);
        split4_k<<<(1179648 / 4 + 255) / 256, 256, 0, stream>>>(
            out_w + (size_t)l * DD * DI, woh, wol, 1179648 / 4);
        splitpad_k<<<(196608 + 255) / 256, 256, 0, stream>>>(
            x_proj + (size_t)l * 80 * DI, xwh, xwl, 80, DI, DI, DI, 196608);
        splitpad_k<<<(98304 + 255) / 256, 256, 0, stream>>>(
            dt_w + (size_t)l * DI * DTR, dwh, dwl, DI, DTR, DTR, 64, 98304);

        // in_proj: (1568,768) x (3072,768)^T -> xz fp32
        mgemm_k<<<dim3(48, 25), 256, 0, stream>>>(hbh, hbl, wih, wil,
            xzb, nullptr, nullptr, M_ROWS, 2 * DI, DD, DD, 2 * DI, nullptr, nullptr, 0);
        // conv + silu -> xc split
        conv_k<<<(M_ROWS * DI) / 256, 256, 0, stream>>>(xzb, conv_w + (size_t)l * DI * DCONV,
                                                        conv_b + (size_t)l * DI, xch, xcl);
        // x_proj: (1568,1536) x (80,1536)^T, split-K=4 atomic -> projb fp32
        fill0_k<<<(M_ROWS * 80 + 255) / 256, 256, 0, stream>>>(projb, M_ROWS * 80);
        mgemm_k<<<dim3(2, 25, 4), 256, 0, stream>>>(xch, xcl, xwh, xwl,
            projb, nullptr, nullptr, M_ROWS, 80, DI, DI, 80, nullptr, nullptr, 3);
        // dt input: proj[:, :48] -> padded split (1600x64)
        splitpad_k<<<(102400 + 255) / 256, 256, 0, stream>>>(
            projb, dih, dil, M_ROWS, DTR, 80, 64, 102400);
        // dt_proj: (1568,64) x (1536,64)^T + bias -> softplus -> split
        mgemm_k<<<dim3(24, 25), 256, 0, stream>>>(dih, dil, dwh, dwl,
            nullptr, doh, dol, M_ROWS, DI, 64, 64, DI, dt_b + (size_t)l * DI, nullptr, 1);
        // chunked scan
        scanA_k<<<dim3(DI / 64, BB, NC), 64, 0, stream>>>(doh, dol, xch, xcl, projb, Al, hpart, sdtb);
        scanB_k<<<dim3(DI / 64, BB), 64, 0, stream>>>(Al, hpart, sdtb, h0b);
        scanC_k<<<dim3(DI / 64, BB, NC), 64, 0, stream>>>(doh, dol, xch, xcl, projb, xzb, Al,
                                                          D_param + (size_t)l * DI, h0b, yh, yl);
        // out_proj: (1568,1536) x (768,1536)^T -> h splits
        mgemm_k<<<dim3(12, 25), 256, 0, stream>>>(yh, yl, woh, wol,
            nullptr, hbh, hbl, M_ROWS, DD, DI, DI, DD, nullptr, nullptr, 0);
    }

    ln_k<<<M_ROWS, 256, 0, stream>>>(hbh, hbl, norm_w, norm_b, out);
}

// Round 6
// 2247.236 us; speedup vs baseline: 1.6013x; 1.0603x over previous
//
#include <hip/hip_runtime.h>

#define BB 8
#define IMG 224
#define DD 768
#define NLAY 12
#define DI 1536
#define DS 16
#define DTR 48
#define NPATCH 196
#define L_SEQ 196
#define M_ROWS 1568   // BB*NPATCH
#define MPAD 1664     // 13*128 row padding for A operands
#define DCONV 4
#define NC 14
#define LC 14

typedef _Float16 f16x8 __attribute__((ext_vector_type(8)));
typedef _Float16 f16x4 __attribute__((ext_vector_type(4)));
typedef float f32x4 __attribute__((ext_vector_type(4)));

__device__ __forceinline__ void gll16(const void* g, void* l) {
    __builtin_amdgcn_global_load_lds(
        (const __attribute__((address_space(1))) unsigned int*)g,
        (__attribute__((address_space(3))) unsigned int*)l,
        16, 0, 0);
}

// ---------------- split fp32 -> (hi,lo) f16, 4 elems/thread ----------------
__global__ __launch_bounds__(256) void split4_k(const float* __restrict__ in,
    _Float16* __restrict__ hi, _Float16* __restrict__ lo, int n4)
{
    int i = blockIdx.x * 256 + threadIdx.x;
    if (i >= n4) return;
    float4 v = ((const float4*)in)[i];
    _Float16 h0 = (_Float16)v.x, h1 = (_Float16)v.y, h2 = (_Float16)v.z, h3 = (_Float16)v.w;
    f16x4 H = {h0, h1, h2, h3};
    f16x4 L = {(_Float16)(v.x - (float)h0), (_Float16)(v.y - (float)h1),
               (_Float16)(v.z - (float)h2), (_Float16)(v.w - (float)h3)};
    ((f16x4*)hi)[i] = H;
    ((f16x4*)lo)[i] = L;
}

// ---------------- layer-batched split with zero padding ----------------
__global__ __launch_bounds__(256) void splitpadN_k(const float* __restrict__ in,
    _Float16* __restrict__ hi, _Float16* __restrict__ lo,
    int perIn, int inRows, int inCols, int outLd, int perOut, int total)
{
    int i = blockIdx.x * 256 + threadIdx.x;
    if (i >= total) return;
    int l = i / perOut, j = i % perOut;
    int r = j / outLd, c = j % outLd;
    float v = (r < inRows && c < inCols) ? in[(size_t)l * perIn + r * inCols + c] : 0.f;
    _Float16 h = (_Float16)v;
    hi[i] = h;
    lo[i] = (_Float16)(v - (float)h);
}

// ---------------- per-layer split with padding (dt input from projb) ----------------
__global__ __launch_bounds__(256) void splitpad_k(const float* __restrict__ in,
    _Float16* __restrict__ hi, _Float16* __restrict__ lo,
    int inRows, int inCols, int inLd, int outLd, int total)
{
    int i = blockIdx.x * 256 + threadIdx.x;
    if (i >= total) return;
    int r = i / outLd, c = i % outLd;
    float v = (r < inRows && c < inCols) ? in[(size_t)r * inLd + c] : 0.f;
    _Float16 h = (_Float16)v;
    hi[i] = h;
    lo[i] = (_Float16)(v - (float)h);
}

// ---------------- im2col with split output ----------------
__global__ __launch_bounds__(256) void im2col_k(const float* __restrict__ x,
    _Float16* __restrict__ hi, _Float16* __restrict__ lo)
{
    int idx = blockIdx.x * 256 + threadIdx.x;
    if (idx >= M_ROWS * DD) return;
    int k = idx % DD;
    int m = idx / DD;
    int b = m / NPATCH;
    int t = m % NPATCH;
    int i = t / 14, j = t % 14;
    int c = k / 256;
    int pq = k % 256;
    int p = pq / 16, q = pq % 16;
    float v = x[(((size_t)b * 3 + c) * IMG + i * 16 + p) * IMG + j * 16 + q];
    _Float16 h = (_Float16)v;
    hi[idx] = h;
    lo[idx] = (_Float16)(v - (float)h);
}

// ---------------- f16x3 MFMA GEMM, 128x128x32, m97-style, swizzled LDS ----------------
// C[M,N] (fp32) = (Ah+Al)[M,K(lda)] * (Bh+Bl)[N,K]^T. A padded to 128-multiple rows.
__global__ __launch_bounds__(256) void mgemm128_k(
    const _Float16* __restrict__ Ah, const _Float16* __restrict__ Al,
    const _Float16* __restrict__ Bh, const _Float16* __restrict__ Bl,
    float* __restrict__ C, int M, int N, int K, int lda)
{
    __shared__ __align__(16) _Float16 As[2][128][32];   // [plane][row][k], seg-swizzled
    __shared__ __align__(16) _Float16 Bs[2][128][32];
    int tid = threadIdx.x, lane = tid & 63, wid = tid >> 6;
    int m0 = blockIdx.y * 128, n0 = blockIdx.x * 128;

    // staging: wave covers rows [r0, r0+32); lane -> row r0+(lane>>2)(+16), seg-swizzled col
    int r0 = wid * 32;
    int lr = lane >> 2;
    int qs = ((lane & 3) ^ ((lane >> 3) & 3)) * 8;   // swizzled global k-seg
    const _Float16* AhP = Ah + (size_t)(m0 + r0 + lr) * lda + qs;
    const _Float16* AlP = Al + (size_t)(m0 + r0 + lr) * lda + qs;
    const _Float16* BhP = Bh + (size_t)(n0 + r0 + lr) * K + qs;
    const _Float16* BlP = Bl + (size_t)(n0 + r0 + lr) * K + qs;
    size_t a16 = (size_t)16 * lda, b16 = (size_t)16 * K;

    int wm = (wid >> 1) * 64, wn = (wid & 1) * 64;
    int lm = lane & 15, quad = lane >> 4;
    int segA = (quad ^ ((lm >> 1) & 3)) * 8;         // read-side swizzle
    f32x4 acc[4][4] = {};

    for (int k0 = 0; k0 < K; k0 += 32) {
        gll16(AhP + k0,       &As[0][r0][0]);
        gll16(AhP + a16 + k0, &As[0][r0 + 16][0]);
        gll16(AlP + k0,       &As[1][r0][0]);
        gll16(AlP + a16 + k0, &As[1][r0 + 16][0]);
        gll16(BhP + k0,       &Bs[0][r0][0]);
        gll16(BhP + b16 + k0, &Bs[0][r0 + 16][0]);
        gll16(BlP + k0,       &Bs[1][r0][0]);
        gll16(BlP + b16 + k0, &Bs[1][r0 + 16][0]);
        __syncthreads();

        f16x8 ah[4], al4[4], bh4[4], bl4[4];
#pragma unroll
        for (int i = 0; i < 4; ++i) {
            ah[i]  = *(const f16x8*)&As[0][wm + i * 16 + lm][segA];
            al4[i] = *(const f16x8*)&As[1][wm + i * 16 + lm][segA];
            bh4[i] = *(const f16x8*)&Bs[0][wn + i * 16 + lm][segA];
            bl4[i] = *(const f16x8*)&Bs[1][wn + i * 16 + lm][segA];
        }
#pragma unroll
        for (int mi = 0; mi < 4; ++mi)
#pragma unroll
            for (int ni = 0; ni < 4; ++ni) {
                acc[mi][ni] = __builtin_amdgcn_mfma_f32_16x16x32_f16(ah[mi],  bh4[ni], acc[mi][ni], 0, 0, 0);
                acc[mi][ni] = __builtin_amdgcn_mfma_f32_16x16x32_f16(ah[mi],  bl4[ni], acc[mi][ni], 0, 0, 0);
                acc[mi][ni] = __builtin_amdgcn_mfma_f32_16x16x32_f16(al4[mi], bh4[ni], acc[mi][ni], 0, 0, 0);
            }
        __syncthreads();
    }

#pragma unroll
    for (int mi = 0; mi < 4; ++mi)
#pragma unroll
        for (int ni = 0; ni < 4; ++ni)
#pragma unroll
            for (int r = 0; r < 4; ++r) {
                int row = m0 + wm + mi * 16 + quad * 4 + r;
                int col = n0 + wn + ni * 16 + lm;
                if (row < M) C[(size_t)row * N + col] = acc[mi][ni][r];
            }
}

// ---------------- f16x3 MFMA GEMM, 64x64x32, dbuf, swizzled ----------------
// mode 0: plain  1: softplus(v+bias[n])  2: v+bias[n]+pos[(m%196)*N+n]  3: atomicAdd (split-K grid.z)
__global__ __launch_bounds__(256) void mgemm_k(
    const _Float16* __restrict__ Ah, const _Float16* __restrict__ Al,
    const _Float16* __restrict__ Bh, const _Float16* __restrict__ Bl,
    float* __restrict__ C, _Float16* __restrict__ Chi, _Float16* __restrict__ Clo,
    int M, int N, int K, int lda, int Nstore,
    const float* __restrict__ bias, const float* __restrict__ pos, int mode)
{
    __shared__ __align__(16) _Float16 As[2][2][64][32];
    __shared__ __align__(16) _Float16 Bs[2][2][64][32];
    int tid = threadIdx.x, lane = tid & 63, wid = tid >> 6;
    int m0 = blockIdx.y * 64, n0 = blockIdx.x * 64;
    int kBeg = 0, nIter = K / 32;
    if (gridDim.z > 1) { int kPer = K / gridDim.z; kBeg = blockIdx.z * kPer; nIter = kPer / 32; }

    int srow = wid * 16 + (lane >> 2);
    int qs = ((lane & 3) ^ ((lane >> 3) & 3)) * 8;
    const _Float16* aH = Ah + (size_t)(m0 + srow) * lda + kBeg + qs;
    const _Float16* aL = Al + (size_t)(m0 + srow) * lda + kBeg + qs;
    const _Float16* bH = Bh + (size_t)(n0 + srow) * K + kBeg + qs;
    const _Float16* bL = Bl + (size_t)(n0 + srow) * K + kBeg + qs;

#define STAGE(buf, it) { int ko = (it) * 32;              \
        gll16(aH + ko, &As[buf][0][wid * 16][0]);          \
        gll16(aL + ko, &As[buf][1][wid * 16][0]);          \
        gll16(bH + ko, &Bs[buf][0][wid * 16][0]);          \
        gll16(bL + ko, &Bs[buf][1][wid * 16][0]); }

    int wm = (wid >> 1) * 32, wn = (wid & 1) * 32;
    int lm = lane & 15, quad = lane >> 4;
    int segA = (quad ^ ((lm >> 1) & 3)) * 8;
    f32x4 acc[2][2] = {};

    STAGE(0, 0);
    for (int it = 0; it < nIter; ++it) {
        int buf = it & 1;
        if (it + 1 < nIter) STAGE(buf ^ 1, it + 1);
        __syncthreads();
        f16x8 ah[2], al2[2], bh2[2], bl2[2];
#pragma unroll
        for (int i = 0; i < 2; ++i) {
            ah[i]  = *(const f16x8*)&As[buf][0][wm + i * 16 + lm][segA];
            al2[i] = *(const f16x8*)&As[buf][1][wm + i * 16 + lm][segA];
            bh2[i] = *(const f16x8*)&Bs[buf][0][wn + i * 16 + lm][segA];
            bl2[i] = *(const f16x8*)&Bs[buf][1][wn + i * 16 + lm][segA];
        }
#pragma unroll
        for (int mi = 0; mi < 2; ++mi)
#pragma unroll
            for (int ni = 0; ni < 2; ++ni) {
                acc[mi][ni] = __builtin_amdgcn_mfma_f32_16x16x32_f16(ah[mi],  bh2[ni], acc[mi][ni], 0, 0, 0);
                acc[mi][ni] = __builtin_amdgcn_mfma_f32_16x16x32_f16(ah[mi],  bl2[ni], acc[mi][ni], 0, 0, 0);
                acc[mi][ni] = __builtin_amdgcn_mfma_f32_16x16x32_f16(al2[mi], bh2[ni], acc[mi][ni], 0, 0, 0);
            }
        __syncthreads();
    }
#undef STAGE

#pragma unroll
    for (int mi = 0; mi < 2; ++mi)
#pragma unroll
        for (int ni = 0; ni < 2; ++ni)
#pragma unroll
            for (int r = 0; r < 4; ++r) {
                int row = m0 + wm + mi * 16 + quad * 4 + r;
                int col = n0 + wn + ni * 16 + lm;
                if (row >= M || col >= Nstore) continue;
                float v = acc[mi][ni][r];
                if (mode == 1) { v += bias[col]; v = (v > 20.f) ? v : log1pf(__expf(v)); }
                else if (mode == 2) v += bias[col] + pos[(size_t)(row % NPATCH) * N + col];
                size_t idx = (size_t)row * N + col;
                if (mode == 3) { atomicAdd(&C[idx], v); continue; }
                if (C) C[idx] = v;
                if (Chi) {
                    _Float16 h = (_Float16)v;
                    Chi[idx] = h;
                    Clo[idx] = (_Float16)(v - (float)h);
                }
            }
}

// ---------------- causal depthwise conv (k=4) + SiLU -> f16 split ----------------
__global__ __launch_bounds__(256) void conv_k(
    const float* __restrict__ xz, const float* __restrict__ cw,
    const float* __restrict__ cb, _Float16* __restrict__ xch, _Float16* __restrict__ xcl)
{
    int idx = blockIdx.x * 256 + threadIdx.x;
    if (idx >= M_ROWS * DI) return;
    int e = idx % DI;
    int m = idx / DI;
    int l = m % L_SEQ;
    float acc = cb[e];
#pragma unroll
    for (int k = 0; k < DCONV; ++k) {
        int ls = l + k - (DCONV - 1);
        if (ls >= 0) acc += cw[e * DCONV + k] * xz[(size_t)(m + k - (DCONV - 1)) * (2 * DI) + e];
    }
    float v = acc / (1.f + __expf(-acc));
    _Float16 h = (_Float16)v;
    xch[idx] = h;
    xcl[idx] = (_Float16)(v - (float)h);
}

// ================= chunked selective scan (3 passes) =================
__global__ __launch_bounds__(64) void scanA_k(
    const _Float16* __restrict__ doh, const _Float16* __restrict__ dol,
    const _Float16* __restrict__ xch, const _Float16* __restrict__ xcl,
    const float* __restrict__ proj, const float* __restrict__ A_log,
    float* __restrict__ hpart, float* __restrict__ Sdt)
{
    int d = blockIdx.x * 64 + threadIdx.x;
    int b = blockIdx.y, c = blockIdx.z;
    float Aa[DS];
#pragma unroll
    for (int s = 0; s < DS; ++s) Aa[s] = -__expf(A_log[d * DS + s]);
    float h[DS];
#pragma unroll
    for (int s = 0; s < DS; ++s) h[s] = 0.f;
    float sdt = 0.f;
    size_t base = (size_t)b * L_SEQ + c * LC;
#pragma unroll 2
    for (int l = 0; l < LC; ++l) {
        size_t ii = (base + l) * DI + d;
        float dtv = (float)doh[ii] + (float)dol[ii];
        float xv  = (float)xch[ii] + (float)xcl[ii];
        const float* pr = proj + (base + l) * 80;
        float dx = dtv * xv;
        sdt += dtv;
#pragma unroll
        for (int s = 0; s < DS; ++s)
            h[s] = __expf(dtv * Aa[s]) * h[s] + dx * pr[DTR + s];
    }
    size_t o = (size_t)(b * NC + c) * DS * DI + d;
#pragma unroll
    for (int s = 0; s < DS; ++s) hpart[o + (size_t)s * DI] = h[s];
    Sdt[(size_t)(b * NC + c) * DI + d] = sdt;
}

__global__ __launch_bounds__(64) void scanB_k(
    const float* __restrict__ A_log, const float* __restrict__ hpart,
    const float* __restrict__ Sdt, float* __restrict__ h0)
{
    int d = blockIdx.x * 64 + threadIdx.x;
    int b = blockIdx.y;
    float Aa[DS];
#pragma unroll
    for (int s = 0; s < DS; ++s) Aa[s] = -__expf(A_log[d * DS + s]);
    float h[DS];
#pragma unroll
    for (int s = 0; s < DS; ++s) h[s] = 0.f;
    for (int c = 0; c < NC; ++c) {
        size_t o = (size_t)(b * NC + c) * DS * DI + d;
#pragma unroll
        for (int s = 0; s < DS; ++s) h0[o + (size_t)s * DI] = h[s];
        float sdt = Sdt[(size_t)(b * NC + c) * DI + d];
#pragma unroll
        for (int s = 0; s < DS; ++s)
            h[s] = __expf(Aa[s] * sdt) * h[s] + hpart[o + (size_t)s * DI];
    }
}

__global__ __launch_bounds__(64) void scanC_k(
    const _Float16* __restrict__ doh, const _Float16* __restrict__ dol,
    const _Float16* __restrict__ xch, const _Float16* __restrict__ xcl,
    const float* __restrict__ proj, const float* __restrict__ xz,
    const float* __restrict__ A_log, const float* __restrict__ Dp,
    const float* __restrict__ h0,
    _Float16* __restrict__ yh, _Float16* __restrict__ yl)
{
    int d = blockIdx.x * 64 + threadIdx.x;
    int b = blockIdx.y, c = blockIdx.z;
    float Aa[DS];
#pragma unroll
    for (int s = 0; s < DS; ++s) Aa[s] = -__expf(A_log[d * DS + s]);
    float h[DS];
    size_t o = (size_t)(b * NC + c) * DS * DI + d;
#pragma unroll
    for (int s = 0; s < DS; ++s) h[s] = h0[o + (size_t)s * DI];
    float dP = Dp[d];
    size_t base = (size_t)b * L_SEQ + c * LC;
#pragma unroll 2
    for (int l = 0; l < LC; ++l) {
        size_t ii = (base + l) * DI + d;
        float dtv = (float)doh[ii] + (float)dol[ii];
        float xv  = (float)xch[ii] + (float)xcl[ii];
        float zv  = xz[(base + l) * 2 * DI + DI + d];
        const float* pr = proj + (base + l) * 80;
        float dx = dtv * xv;
        float accv = 0.f;
#pragma unroll
        for (int s = 0; s < DS; ++s) {
            h[s] = __expf(dtv * Aa[s]) * h[s] + dx * pr[DTR + s];
            accv += h[s] * pr[DTR + DS + s];
        }
        float yv = accv + xv * dP;
        float sg = 1.f / (1.f + __expf(-zv));
        float vy = yv * (zv * sg);
        _Float16 hh = (_Float16)vy;
        yh[ii] = hh;
        yl[ii] = (_Float16)(vy - (float)hh);
    }
}

// ---------------- layernorm over D=768 from f16 hi+lo ----------------
__global__ __launch_bounds__(256) void ln_k(const _Float16* __restrict__ hh,
    const _Float16* __restrict__ hl,
    const float* __restrict__ w, const float* __restrict__ bias, float* __restrict__ out)
{
    int row = blockIdx.x;
    int tid = threadIdx.x;
    size_t base = (size_t)row * DD;
    float v0 = (float)hh[base + tid]       + (float)hl[base + tid];
    float v1 = (float)hh[base + tid + 256] + (float)hl[base + tid + 256];
    float v2 = (float)hh[base + tid + 512] + (float)hl[base + tid + 512];
    float s = v0 + v1 + v2;
    __shared__ float red[4];
    for (int off = 32; off; off >>= 1) s += __shfl_down(s, off);
    if ((tid & 63) == 0) red[tid >> 6] = s;
    __syncthreads();
    float mu = (red[0] + red[1] + red[2] + red[3]) * (1.f / 768.f);
    __syncthreads();
    float d0 = v0 - mu, d1 = v1 - mu, d2 = v2 - mu;
    float vs = d0 * d0 + d1 * d1 + d2 * d2;
    for (int off = 32; off; off >>= 1) vs += __shfl_down(vs, off);
    if ((tid & 63) == 0) red[tid >> 6] = vs;
    __syncthreads();
    float var = (red[0] + red[1] + red[2] + red[3]) * (1.f / 768.f);
    float rs = rsqrtf(var + 1e-5f);
    out[base + tid]       = d0 * rs * w[tid]       + bias[tid];
    out[base + tid + 256] = d1 * rs * w[tid + 256] + bias[tid + 256];
    out[base + tid + 512] = d2 * rs * w[tid + 512] + bias[tid + 512];
}

__global__ __launch_bounds__(256) void fill0_k(float* __restrict__ p, int n) {
    int i = blockIdx.x * 256 + threadIdx.x;
    if (i < n) p[i] = 0.f;
}

extern "C" void kernel_launch(void* const* d_in, const int* in_sizes, int n_in,
                              void* d_out, int out_size, void* d_ws, size_t ws_size,
                              hipStream_t stream) {
    const float* x        = (const float*)d_in[0];
    const float* patch_w  = (const float*)d_in[1];
    const float* patch_b  = (const float*)d_in[2];
    const float* pos      = (const float*)d_in[3];
    const float* in_proj  = (const float*)d_in[4];
    const float* conv_w   = (const float*)d_in[5];
    const float* conv_b   = (const float*)d_in[6];
    const float* x_proj   = (const float*)d_in[7];
    const float* dt_w     = (const float*)d_in[8];
    const float* dt_b     = (const float*)d_in[9];
    const float* A_log    = (const float*)d_in[10];
    const float* D_param  = (const float*)d_in[11];
    const float* out_w    = (const float*)d_in[12];
    const float* norm_w   = (const float*)d_in[13];
    const float* norm_b   = (const float*)d_in[14];
    float* out = (float*)d_out;

    // fp32 workspace
    float* ws    = (float*)d_ws;
    float* xzb   = ws;                      // 4,816,896
    float* projb = xzb   + 4816896;         //   125,440
    float* hpart = projb + 125440;          // 2,752,512
    float* h0b   = hpart + 2752512;         // 2,752,512
    float* sdtb  = h0b   + 2752512;         //   172,032
    // f16 workspace (A-operand buffers padded to MPAD=1664 rows)
    _Float16* fp  = (_Float16*)(sdtb + 172032);
    _Float16* hbh = fp;                     // 1664*768
    _Float16* hbl = hbh + MPAD * DD;
    _Float16* yh  = hbl + MPAD * DD;        // 1664*1536 (also im2col out)
    _Float16* yl  = yh  + MPAD * DI;
    _Float16* xch = yl  + MPAD * DI;        // 1664*1536
    _Float16* xcl = xch + MPAD * DI;
    _Float16* doh = xcl + MPAD * DI;        // 1568*1536
    _Float16* dol = doh + M_ROWS * DI;
    _Float16* dih = dol + M_ROWS * DI;      // 1664*64
    _Float16* dil = dih + MPAD * 64;
    _Float16* pwh = dil + MPAD * 64;        // 768*768
    _Float16* pwl = pwh + 589824;
    // all-layer weight splits
    _Float16* wih = pwl + 589824;           // 12 * 3072*768
    _Float16* wil = wih + (size_t)NLAY * 2359296;
    _Float16* woh = wil + (size_t)NLAY * 2359296;   // 12 * 768*1536
    _Float16* wol = woh + (size_t)NLAY * 1179648;
    _Float16* xwh = wol + (size_t)NLAY * 1179648;   // 12 * 128*1536 (row-padded)
    _Float16* xwl = xwh + (size_t)NLAY * 196608;
    _Float16* dwh = xwl + (size_t)NLAY * 196608;    // 12 * 1536*64 (col-padded)
    _Float16* dwl = dwh + (size_t)NLAY * 98304;

    // ---- all weight splits, batched over layers (4+1 launches) ----
    split4_k<<<(NLAY * 2359296 / 4 + 255) / 256, 256, 0, stream>>>(in_proj, wih, wil, NLAY * 2359296 / 4);
    split4_k<<<(NLAY * 1179648 / 4 + 255) / 256, 256, 0, stream>>>(out_w, woh, wol, NLAY * 1179648 / 4);
    splitpadN_k<<<(NLAY * 196608 + 255) / 256, 256, 0, stream>>>(
        x_proj, xwh, xwl, 80 * DI, 80, DI, DI, 196608, NLAY * 196608);
    splitpadN_k<<<(NLAY * 98304 + 255) / 256, 256, 0, stream>>>(
        dt_w, dwh, dwl, DI * DTR, DI, DTR, 64, 98304, NLAY * 98304);
    split4_k<<<(589824 / 4 + 255) / 256, 256, 0, stream>>>(patch_w, pwh, pwl, 589824 / 4);

    // ---- patch embed ----
    im2col_k<<<(M_ROWS * DD + 255) / 256, 256, 0, stream>>>(x, yh, yl);
    mgemm_k<<<dim3(12, 25), 256, 0, stream>>>(yh, yl, pwh, pwl,
        nullptr, hbh, hbl, M_ROWS, DD, DD, DD, DD, patch_b, pos, 2);

    for (int l = 0; l < NLAY; ++l) {
        const float* Al = A_log + (size_t)l * DI * DS;
        // in_proj: (1568,768) x (3072,768)^T -> xz fp32 (128x128 kernel)
        mgemm128_k<<<dim3(24, 13), 256, 0, stream>>>(hbh, hbl,
            wih + (size_t)l * 2359296, wil + (size_t)l * 2359296,
            xzb, M_ROWS, 2 * DI, DD, DD);
        // conv + silu -> xc split
        conv_k<<<(M_ROWS * DI) / 256, 256, 0, stream>>>(xzb, conv_w + (size_t)l * DI * DCONV,
                                                        conv_b + (size_t)l * DI, xch, xcl);
        // x_proj: split-K=4 atomic -> projb fp32
        fill0_k<<<(M_ROWS * 80 + 255) / 256, 256, 0, stream>>>(projb, M_ROWS * 80);
        mgemm_k<<<dim3(2, 25, 4), 256, 0, stream>>>(xch, xcl,
            xwh + (size_t)l * 196608, xwl + (size_t)l * 196608,
            projb, nullptr, nullptr, M_ROWS, 80, DI, DI, 80, nullptr, nullptr, 3);
        // dt input: proj[:, :48] -> padded split (1664x64, zero pad)
        splitpad_k<<<(MPAD * 64 + 255) / 256, 256, 0, stream>>>(
            projb, dih, dil, M_ROWS, DTR, 80, 64, MPAD * 64);
        // dt_proj + softplus -> split
        mgemm_k<<<dim3(24, 25), 256, 0, stream>>>(dih, dil,
            dwh + (size_t)l * 98304, dwl + (size_t)l * 98304,
            nullptr, doh, dol, M_ROWS, DI, 64, 64, DI, dt_b + (size_t)l * DI, nullptr, 1);
        // chunked scan
        scanA_k<<<dim3(DI / 64, BB, NC), 64, 0, stream>>>(doh, dol, xch, xcl, projb, Al, hpart, sdtb);
        scanB_k<<<dim3(DI / 64, BB), 64, 0, stream>>>(Al, hpart, sdtb, h0b);
        scanC_k<<<dim3(DI / 64, BB, NC), 64, 0, stream>>>(doh, dol, xch, xcl, projb, xzb, Al,
                                                          D_param + (size_t)l * DI, h0b, yh, yl);
        // out_proj -> h splits
        mgemm_k<<<dim3(12, 25), 256, 0, stream>>>(yh, yl,
            woh + (size_t)l * 1179648, wol + (size_t)l * 1179648,
            nullptr, hbh, hbl, M_ROWS, DD, DI, DI, DD, nullptr, nullptr, 0);
    }

    ln_k<<<M_ROWS, 256, 0, stream>>>(hbh, hbl, norm_w, norm_b, out);
}